// Round 16
// baseline (206.049 us; speedup 1.0000x reference)
//
#include <hip/hip_runtime.h>
#include <hip/hip_bf16.h>
#include <stdint.h>

// Problem shape (fixed): inputs [4,2048,1024] f32, key [4096,1024] f32, value [4096,1024] f32
#define M_ROWS 8192   // B*L
#define D_DIM  1024
#define S_DIM  4096
#define DV_DIM 1024

typedef __attribute__((ext_vector_type(8))) short bf16x8;
typedef __attribute__((ext_vector_type(4))) float f32x4;
typedef unsigned short u16;

static __device__ __forceinline__ u16 f2bf(float x) {
  union { float f; unsigned u; } v; v.f = x;
  unsigned r = v.u + 0x7FFFu + ((v.u >> 16) & 1u);   // RNE
  return (u16)(r >> 16);
}
static __device__ __forceinline__ float bf2f(u16 h) {
  union { unsigned u; float f; } v; v.u = ((unsigned)h) << 16;
  return v.f;
}
// tanh-form gelu; |err vs exact erf-gelu| < ~1e-3, fine at this tolerance
static __device__ __forceinline__ float gelu_fast(float x) {
  float u = 0.7978845608028654f * x * (1.0f + 0.044715f * x * x);
  float e = __expf(2.0f * u);
  float t = 1.0f - 2.0f / (e + 1.0f);   // tanh(u)
  return 0.5f * x * (1.0f + t);
}

static __device__ __forceinline__ void gload16(const void* g, void* l) {
  __builtin_amdgcn_global_load_lds(
      (__attribute__((address_space(1))) void*)(void*)(g),
      (__attribute__((address_space(3))) void*)(l), 16, 0, 0);
}

// ---------------- cast f32 -> bf16 ----------------
__global__ __launch_bounds__(256)
void cast_f32_bf16(const float* __restrict__ in, u16* __restrict__ out, int n4) {
  const int i = blockIdx.x * 256 + threadIdx.x;
  if (i >= n4) return;
  const float4 v = ((const float4*)in)[i];
  ushort4 o;
  o.x = f2bf(v.x); o.y = f2bf(v.y); o.z = f2bf(v.z); o.w = f2bf(v.w);
  ((ushort4*)out)[i] = o;
}

// ------------- transpose + cast: V [R,C] f32 -> VT [C,R] bf16 -------------
__global__ __launch_bounds__(256)
void transpose_cast(const float* __restrict__ V, u16* __restrict__ VT, int R, int C) {
  __shared__ float tile[32][33];
  const int tx = threadIdx.x & 31;
  const int ty = threadIdx.x >> 5;
  const int r0 = blockIdx.y * 32;
  const int c0 = blockIdx.x * 32;
#pragma unroll
  for (int dy = 0; dy < 32; dy += 8)
    tile[ty + dy][tx] = V[(long)(r0 + ty + dy) * C + (c0 + tx)];
  __syncthreads();
#pragma unroll
  for (int dy = 0; dy < 32; dy += 8)
    VT[(long)(c0 + ty + dy) * R + (r0 + tx)] = f2bf(tile[tx][ty + dy]);
}

// ------------- per-row sum(g^2) -> scale = 64 * rsqrt(ssq) -------------
__global__ __launch_bounds__(256)
void row_scale(const u16* __restrict__ G, float* __restrict__ scale, int S) {
  const int row = blockIdx.x;
  const u16* g = G + (long)row * S;
  float ssq = 0.f;
  for (int i = threadIdx.x * 8; i < S; i += 256 * 8) {
    bf16x8 v = *(const bf16x8*)&g[i];
#pragma unroll
    for (int j = 0; j < 8; ++j) {
      float f = bf2f((u16)v[j]);
      ssq += f * f;
    }
  }
#pragma unroll
  for (int off = 32; off > 0; off >>= 1)
    ssq += __shfl_down(ssq, off, 64);
  __shared__ float wsum[4];
  if ((threadIdx.x & 63) == 0) wsum[threadIdx.x >> 6] = ssq;
  __syncthreads();
  if (threadIdx.x == 0) {
    float t = wsum[0] + wsum[1] + wsum[2] + wsum[3];
    scale[row] = 64.0f * rsqrtf(t + 1e-30f);
  }
}

// ------------- Out[i] += P1[i]  (split-K reduce) -------------
__global__ __launch_bounds__(256)
void add_inplace(float* __restrict__ Out, const float* __restrict__ P1, int n4) {
  for (int i = blockIdx.x * 256 + threadIdx.x; i < n4; i += 2048 * 256) {
    float4 a = ((const float4*)Out)[i];
    const float4 b = ((const float4*)P1)[i];
    a.x += b.x; a.y += b.y; a.z += b.z; a.w += b.w;
    ((float4*)Out)[i] = a;
  }
}

// =============== fat-wave 256x256 GEMM: C = A[M,K] * Bm[N,K]^T ===============
// 4 waves (2M x 2N), wave tile 128x128, BK=64, double-buffered LDS (128 KB),
// row&7 chunk swizzle, asm barriers, setprio around MFMA.
// MECHANISM vs the 8-wave anchor: per-wave output tile 128x64 -> 128x128 cuts
// LDS fragment bytes/FLOP by 1.5x (A-panel was read 4x redundantly by the 4
// wn-waves). Per-CU per-K-tile LDS drops 192KB (~2300cyc) -> 128KB (~1540cyc),
// now below the 2480cyc MFMA wall. Cost: acc 256 VGPR + bfr 64 -> ~370 VGPR,
// 1 wave/SIMD (launch_bounds(256,1); no-spill bound measured at 450).
// Ledger (R2-family, scaled to 16 staging calls of 4KB; fixpoint-checked):
//  prologue: B0-7(t0), A{0,4,1,5,2,6,3,7}(t0), VMW(4) -> leaves {A2,A6,A3,A7}
//  tile kt:  ph0 +B0-3(nxt) | ph1 +B4-7(nxt), VMW(10) retires A2,A6(cur)
//            ph2 +A{0,4,1,5}(nxt), VMW(8) retires A3,A7(cur)+B0-3(nxt)
//            ph3 +A{2,6,3,7}(nxt), VMW(4) -> invariant {A2,A6,A3,A7}(nxt)
//  ph P reads A rows wm*128+[P*32,P*32+31] = calls P (wm=0) and P+4 (wm=1);
//  every waited call has >=1 phase (>=~1000cyc) slack; all stages target the
//  INACTIVE buffer (same hazard profile as the thrice-validated anchor).
// MODE 0: C = gelu(acc)->bf16.  MODE 1: C = acc*scale[row]->f32.
// SPLITK: two K-slices (strides lda/ldb), C0 (ks=0) / C1 (ks=1).

#define BARRIER asm volatile("s_barrier" ::: "memory")
#define VMW(N) asm volatile("s_waitcnt vmcnt(" #N ")" ::: "memory")

#define PHASE(P, STAGES, WAITS)                                               \
  {                                                                           \
    bf16x8 af[2][2];                                                          \
    _Pragma("unroll")                                                         \
    for (int j = 0; j < 2; ++j) {                                             \
      const int ar = wm * 128 + ((P) * 2 + j) * 16 + fr;                      \
      af[j][0] = rdfrag(la, ar, 0);                                           \
      af[j][1] = rdfrag(la, ar, 1);                                           \
    }                                                                         \
    STAGES;                                                                   \
    BARRIER;                                                                  \
    __builtin_amdgcn_s_setprio(1);                                            \
    _Pragma("unroll")                                                         \
    for (int j = 0; j < 2; ++j) {                                             \
      _Pragma("unroll")                                                       \
      for (int n = 0; n < 8; ++n) {                                           \
        acc[(P) * 2 + j][n] = __builtin_amdgcn_mfma_f32_16x16x32_bf16(        \
            af[j][0], bfr[n][0], acc[(P) * 2 + j][n], 0, 0, 0);               \
        acc[(P) * 2 + j][n] = __builtin_amdgcn_mfma_f32_16x16x32_bf16(        \
            af[j][1], bfr[n][1], acc[(P) * 2 + j][n], 0, 0, 0);               \
      }                                                                       \
    }                                                                         \
    __builtin_amdgcn_s_setprio(0);                                            \
    WAITS;                                                                    \
    BARRIER;                                                                  \
  }

#define READ_B                                                                \
  {                                                                           \
    _Pragma("unroll")                                                         \
    for (int n = 0; n < 8; ++n) {                                             \
      const int br = wn * 128 + n * 16 + fr;                                  \
      bfr[n][0] = rdfrag(lb, br, 0);                                          \
      bfr[n][1] = rdfrag(lb, br, 1);                                          \
    }                                                                         \
  }

template <int MODE, bool SPLITK>
__global__ __launch_bounds__(256, 1)
void gemm4f(const u16* __restrict__ A, const u16* __restrict__ Bm,
            void* __restrict__ Cout0, void* __restrict__ Cout1,
            const float* __restrict__ scale,
            const int K, const int lda, const int ldb,
            const int N, const int nBN, const int nWG) {
  constexpr int BM = 256, BN = 256, BK = 64;

  __shared__ u16 ldsA[2][BM * BK];   // 2 x 32 KB
  __shared__ u16 ldsB[2][BN * BK];   // 2 x 32 KB

  const int tid = threadIdx.x;
  const int lane = tid & 63;
  const int wv = tid >> 6;           // 4 waves: 2M x 2N
  const int wm = wv >> 1, wn = wv & 1;
  const int fr = lane & 15, hi = lane >> 4;

  // bijective XCD swizzle (m204)
  int wg;
  {
    const int q = nWG >> 3, r = nWG & 7;
    const int x = blockIdx.x & 7, ix = blockIdx.x >> 3;
    wg = (x < r ? x * (q + 1) : r * (q + 1) + (x - r) * q) + ix;
  }
  // split-K slice decode
  void* Cout = Cout0;
  if constexpr (SPLITK) {
    const int half = nWG >> 1;
    const int ks = (wg >= half) ? 1 : 0;
    wg -= ks * half;
    A += (long)ks * K;
    Bm += (long)ks * K;
    if (ks) Cout = Cout1;
  }
  const int bm = wg / nBN, bn = wg % nBN;
  const long aR0 = (long)bm * BM;
  const long bR0 = (long)bn * BN;

  // staging: each call covers 32 rows x 8 chunks of 16B (4 KB);
  // slot (row, s) holds global chunk s^(row&7)
  const int srow = tid >> 3;         // 0..31
  const int sch = (tid & 7) ^ (srow & 7);
  const long aoff = (aR0 + srow) * (long)lda + sch * 8;
  const long boff = (bR0 + srow) * (long)ldb + sch * 8;

  auto SA = [&](int buf, int r, int kOff) {
    gload16(A + aoff + ((long)r * 32) * lda + kOff, &ldsA[buf][r * 2048 + tid * 8]);
  };
  auto SB = [&](int buf, int r, int kOff) {
    gload16(Bm + boff + ((long)r * 32) * ldb + kOff, &ldsB[buf][r * 2048 + tid * 8]);
  };
  // swizzled ds_read_b128: chunk = (kk*4 + hi) ^ (row&7)
  auto rdfrag = [&](const u16* base, int row, int kk) -> bf16x8 {
    return *(const bf16x8*)&base[row * 64 + (((kk << 2) | hi) ^ (row & 7)) * 8];
  };

  f32x4 acc[8][8];
#pragma unroll
  for (int m = 0; m < 8; ++m)
#pragma unroll
    for (int n = 0; n < 8; ++n)
      acc[m][n] = f32x4{0.f, 0.f, 0.f, 0.f};

  bf16x8 bfr[8][2];
  const int nK = K / BK;

  // ---- prologue: B0-7(t0), A in phase-need order, wait all but last 4 ----
  SB(0, 0, 0); SB(0, 1, 0); SB(0, 2, 0); SB(0, 3, 0);
  SB(0, 4, 0); SB(0, 5, 0); SB(0, 6, 0); SB(0, 7, 0);
  SA(0, 0, 0); SA(0, 4, 0); SA(0, 1, 0); SA(0, 5, 0);
  SA(0, 2, 0); SA(0, 6, 0); SA(0, 3, 0); SA(0, 7, 0);
  VMW(4);   // leaves {A2,A6,A3,A7} — read in ph2/ph3, retired by then
  BARRIER;

  // ---- main loop: tile kt reads buf cur, stages tile kt+1 into cur^1 ----
  int cur = 0;
  for (int kt = 0; kt < nK - 1; ++kt) {
    const int kN = (kt + 1) * BK;
    const int nxt = cur ^ 1;
    const u16* la = ldsA[cur];
    const u16* lb = ldsB[cur];
    READ_B;
    PHASE(0, { SB(nxt, 0, kN); SB(nxt, 1, kN); SB(nxt, 2, kN); SB(nxt, 3, kN); }, {});
    PHASE(1, { SB(nxt, 4, kN); SB(nxt, 5, kN); SB(nxt, 6, kN); SB(nxt, 7, kN); }, VMW(10));
    PHASE(2, { SA(nxt, 0, kN); SA(nxt, 4, kN); SA(nxt, 1, kN); SA(nxt, 5, kN); }, VMW(8));
    PHASE(3, { SA(nxt, 2, kN); SA(nxt, 6, kN); SA(nxt, 3, kN); SA(nxt, 7, kN); }, VMW(4));
    cur ^= 1;
  }

  // ---- final tile: no staging; {A2,A6,A3,A7} in flight until phase-1 wait ----
  {
    const u16* la = ldsA[cur];
    const u16* lb = ldsB[cur];
    READ_B;
    PHASE(0, {}, {});
    PHASE(1, {}, VMW(0));
    PHASE(2, {}, {});
    PHASE(3, {}, {});
  }

  // ---- epilogue; C/D: col=fr, row=hi*4+i ----
  const long row0 = aR0 + wm * 128;
  const long col0 = bR0 + wn * 128;
  if constexpr (MODE == 0) {
    u16* Cg = (u16*)Cout;
#pragma unroll
    for (int m = 0; m < 8; ++m) {
#pragma unroll
      for (int i = 0; i < 4; ++i) {
        const long r = row0 + m * 16 + hi * 4 + i;
#pragma unroll
        for (int n = 0; n < 8; ++n)
          Cg[r * N + col0 + n * 16 + fr] = f2bf(gelu_fast(acc[m][n][i]));
      }
    }
  } else {
    float* Cf = (float*)Cout;
#pragma unroll
    for (int m = 0; m < 8; ++m) {
#pragma unroll
      for (int i = 0; i < 4; ++i) {
        const long r = row0 + m * 16 + hi * 4 + i;
        const float s = scale[r];
#pragma unroll
        for (int n = 0; n < 8; ++n)
          Cf[r * N + col0 + n * 16 + fr] = acc[m][n][i] * s;
      }
    }
  }
}

extern "C" void kernel_launch(void* const* d_in, const int* in_sizes, int n_in,
                              void* d_out, int out_size, void* d_ws, size_t ws_size,
                              hipStream_t stream) {
  const float* Qf = (const float*)d_in[0];
  const float* Kf = (const float*)d_in[1];
  const float* Vf = (const float*)d_in[2];
  float* Out = (float*)d_out;

  const int M = M_ROWS, D = D_DIM, S = S_DIM, DV = DV_DIM;

  // workspace layout
  char* p = (char*)d_ws;
  u16* Qb = (u16*)p;            p += (size_t)M * D * 2;    // 16 MB
  u16* Kb = (u16*)p;            p += (size_t)S * D * 2;    //  8 MB
  u16* VT = (u16*)p;            p += (size_t)DV * S * 2;   //  8 MB
  float* scalebuf = (float*)p;  p += (size_t)M * 4;        // 32 KB
  u16* G = (u16*)p;                                        // 64 MB when unchunked
  const size_t fixed = (size_t)(p - (char*)d_ws);
  const size_t avail = (ws_size > fixed) ? (ws_size - fixed) : 0;

  // M-chunking (multiples of 256) so the G panel fits
  const size_t bytes_per_row = (size_t)S * 2;
  size_t rows_fit = avail / bytes_per_row;
  int chunk = (int)((rows_fit / 256) * 256);
  if (chunk > M) chunk = M;
  if (chunk < 256) chunk = 256;

  // split-K path needs G (full) + 32 MB f32 partial after it
  const size_t Gbytes = (size_t)M * S * 2;
  const size_t Pbytes = (size_t)M * DV * 4;
  const bool use_split = (chunk >= M) && (avail >= Gbytes + Pbytes);
  float* P1 = (float*)((char*)G + Gbytes);

  cast_f32_bf16<<<(M * D / 4 + 255) / 256, 256, 0, stream>>>(Qf, Qb, M * D / 4);
  cast_f32_bf16<<<(S * D / 4 + 255) / 256, 256, 0, stream>>>(Kf, Kb, S * D / 4);
  transpose_cast<<<dim3(DV / 32, S / 32), 256, 0, stream>>>(Vf, VT, S, DV);

  const int nBN1 = S / 256;    // 16
  const int nBN2 = DV / 256;   // 4
  for (int m0 = 0; m0 < M; m0 += chunk) {
    const int rows = (M - m0 < chunk) ? (M - m0) : chunk;
    const int nWG1 = (rows / 256) * nBN1;
    gemm4f<0, false><<<dim3(nWG1), 256, 0, stream>>>(
        Qb + (size_t)m0 * D, Kb, (void*)G, nullptr, nullptr, D, D, D, S, nBN1, nWG1);
    row_scale<<<rows, 256, 0, stream>>>(G, scalebuf, S);
    if (use_split) {
      // two K=2048 slices, one 256-block launch (1 block/CU)
      const int nWGs = 2 * (M / 256) * nBN2;   // 256
      gemm4f<1, true><<<dim3(nWGs), 256, 0, stream>>>(
          G, VT, (void*)Out, (void*)P1, scalebuf, S / 2, S, S, DV, nBN2, nWGs);
      add_inplace<<<2048, 256, 0, stream>>>(Out, P1, M * DV / 4);
    } else {
      const int nWG2 = (rows / 256) * nBN2;
      gemm4f<1, false><<<dim3(nWG2), 256, 0, stream>>>(
          G, VT, (void*)(Out + (size_t)m0 * DV), nullptr, scalebuf, S, S, S, DV, nBN2, nWG2);
    }
  }
}

// Round 17
// 190.673 us; speedup vs baseline: 1.0806x; 1.0806x over previous
//
#include <hip/hip_runtime.h>
#include <hip/hip_bf16.h>
#include <stdint.h>

// Problem shape (fixed): inputs [4,2048,1024] f32, key [4096,1024] f32, value [4096,1024] f32
#define M_ROWS 8192   // B*L
#define D_DIM  1024
#define S_DIM  4096
#define DV_DIM 1024

typedef __attribute__((ext_vector_type(8))) short bf16x8;
typedef __attribute__((ext_vector_type(4))) float f32x4;
typedef unsigned short u16;

static __device__ __forceinline__ u16 f2bf(float x) {
  union { float f; unsigned u; } v; v.f = x;
  unsigned r = v.u + 0x7FFFu + ((v.u >> 16) & 1u);   // RNE
  return (u16)(r >> 16);
}
static __device__ __forceinline__ float bf2f(u16 h) {
  union { unsigned u; float f; } v; v.u = ((unsigned)h) << 16;
  return v.f;
}
// tanh-form gelu; |err vs exact erf-gelu| < ~1e-3, fine at this tolerance
static __device__ __forceinline__ float gelu_fast(float x) {
  float u = 0.7978845608028654f * x * (1.0f + 0.044715f * x * x);
  float e = __expf(2.0f * u);
  float t = 1.0f - 2.0f / (e + 1.0f);   // tanh(u)
  return 0.5f * x * (1.0f + t);
}

static __device__ __forceinline__ void gload16(const void* g, void* l) {
  __builtin_amdgcn_global_load_lds(
      (__attribute__((address_space(1))) void*)(void*)(g),
      (__attribute__((address_space(3))) void*)(l), 16, 0, 0);
}

// ---------------- cast f32 -> bf16 ----------------
__global__ __launch_bounds__(256)
void cast_f32_bf16(const float* __restrict__ in, u16* __restrict__ out, int n4) {
  const int i = blockIdx.x * 256 + threadIdx.x;
  if (i >= n4) return;
  const float4 v = ((const float4*)in)[i];
  ushort4 o;
  o.x = f2bf(v.x); o.y = f2bf(v.y); o.z = f2bf(v.z); o.w = f2bf(v.w);
  ((ushort4*)out)[i] = o;
}

// ------------- transpose + cast: V [R,C] f32 -> VT [C,R] bf16 -------------
__global__ __launch_bounds__(256)
void transpose_cast(const float* __restrict__ V, u16* __restrict__ VT, int R, int C) {
  __shared__ float tile[32][33];
  const int tx = threadIdx.x & 31;
  const int ty = threadIdx.x >> 5;
  const int r0 = blockIdx.y * 32;
  const int c0 = blockIdx.x * 32;
#pragma unroll
  for (int dy = 0; dy < 32; dy += 8)
    tile[ty + dy][tx] = V[(long)(r0 + ty + dy) * C + (c0 + tx)];
  __syncthreads();
#pragma unroll
  for (int dy = 0; dy < 32; dy += 8)
    VT[(long)(c0 + ty + dy) * R + (r0 + tx)] = f2bf(tile[tx][ty + dy]);
}

// ------------- per-row sum(g^2) -> scale = 64 * rsqrt(ssq) -------------
__global__ __launch_bounds__(256)
void row_scale(const u16* __restrict__ G, float* __restrict__ scale, int S) {
  const int row = blockIdx.x;
  const u16* g = G + (long)row * S;
  float ssq = 0.f;
  for (int i = threadIdx.x * 8; i < S; i += 256 * 8) {
    bf16x8 v = *(const bf16x8*)&g[i];
#pragma unroll
    for (int j = 0; j < 8; ++j) {
      float f = bf2f((u16)v[j]);
      ssq += f * f;
    }
  }
#pragma unroll
  for (int off = 32; off > 0; off >>= 1)
    ssq += __shfl_down(ssq, off, 64);
  __shared__ float wsum[4];
  if ((threadIdx.x & 63) == 0) wsum[threadIdx.x >> 6] = ssq;
  __syncthreads();
  if (threadIdx.x == 0) {
    float t = wsum[0] + wsum[1] + wsum[2] + wsum[3];
    scale[row] = 64.0f * rsqrtf(t + 1e-30f);
  }
}

// ------------- Out[i] += P1[i]  (split-K reduce) -------------
__global__ __launch_bounds__(256)
void add_inplace(float* __restrict__ Out, const float* __restrict__ P1, int n4) {
  for (int i = blockIdx.x * 256 + threadIdx.x; i < n4; i += 2048 * 256) {
    float4 a = ((const float4*)Out)[i];
    const float4 b = ((const float4*)P1)[i];
    a.x += b.x; a.y += b.y; a.z += b.z; a.w += b.w;
    ((float4*)Out)[i] = a;
  }
}

// =================== 8-phase 256-wide GEMM: C = A[M,K] * Bm[N,K]^T ===================
// MODE 0 (BN=256): C = gelu(acc) -> bf16    MODE 1: C = acc*scale[row] -> f32
// SPLITK: two K-slices in one launch (strides lda/ldb), C0 (ks=0) / C1 (ks=1).
// 8 waves (2M x 4N), BK=64, double-buffered LDS, counted vmcnt, row&7 chunk swizzle.
// FINAL session configuration (thrice-validated: R10/R13/R15, 191 us total,
// 87.3 us/GEMM = 787 TF = 31.5% dense bf16 peak). Ten variants bracketed
// 25-32% MfmaUtil: vmcnt ledgers x4, split-K, 2-blk/CU, fat-wave 128x128,
// no-lgkm-drain, asm-barrier, barrier-free. Constraint: LDS-read issue pipe
// (24 b128/wave/K-tile x 12cyc) needs >=2 waves/SIMD to hide, but 2 waves/SIMD
// caps VGPR at 256 which caps wave-tile at 128x64 — traffic reduction and
// latency hiding are mutually exclusive at this register budget. Escape needs
// instruction-level pipeline codegen (m201/HK class), not reachable from
// source-level description (ten ports; consistent with learn_hip m232 OPEN).

#define BARRIER asm volatile("s_barrier" ::: "memory")
#define VM4 asm volatile("s_waitcnt vmcnt(4)" ::: "memory")
#define VM2 asm volatile("s_waitcnt vmcnt(2)" ::: "memory")
#define VM0 asm volatile("s_waitcnt vmcnt(0)" ::: "memory")

#define PHASE(P, STAGES, WAITS)                                               \
  {                                                                           \
    bf16x8 af[2][2];                                                          \
    _Pragma("unroll")                                                         \
    for (int j = 0; j < 2; ++j) {                                             \
      const int ar = wm * 128 + ((P) * 2 + j) * 16 + fr;                      \
      af[j][0] = rdfrag(la, ar, 0);                                           \
      af[j][1] = rdfrag(la, ar, 1);                                           \
    }                                                                         \
    STAGES;                                                                   \
    BARRIER;                                                                  \
    __builtin_amdgcn_s_setprio(1);                                            \
    _Pragma("unroll")                                                         \
    for (int j = 0; j < 2; ++j) {                                             \
      _Pragma("unroll")                                                       \
      for (int n = 0; n < NF; ++n) {                                          \
        acc[(P) * 2 + j][n] = __builtin_amdgcn_mfma_f32_16x16x32_bf16(        \
            af[j][0], bfr[n][0], acc[(P) * 2 + j][n], 0, 0, 0);               \
        acc[(P) * 2 + j][n] = __builtin_amdgcn_mfma_f32_16x16x32_bf16(        \
            af[j][1], bfr[n][1], acc[(P) * 2 + j][n], 0, 0, 0);               \
      }                                                                       \
    }                                                                         \
    __builtin_amdgcn_s_setprio(0);                                            \
    WAITS;                                                                    \
    BARRIER;                                                                  \
  }

#define READ_B                                                                \
  {                                                                           \
    _Pragma("unroll")                                                         \
    for (int n = 0; n < NF; ++n) {                                            \
      const int br = wn * WNT + n * 16 + fr;                                  \
      bfr[n][0] = rdfrag(lb, br, 0);                                          \
      bfr[n][1] = rdfrag(lb, br, 1);                                          \
    }                                                                         \
  }

template <int MODE, int BN, bool SPLITK>
__global__ __launch_bounds__(512, 2)
void gemm8p(const u16* __restrict__ A, const u16* __restrict__ Bm,
            void* __restrict__ Cout0, void* __restrict__ Cout1,
            const float* __restrict__ scale,
            const int K, const int lda, const int ldb,
            const int N, const int nBN, const int nWG) {
  constexpr int BM = 256, BK = 64;
  constexpr int WNT = BN / 4;     // 64 or 32
  constexpr int NF = WNT / 16;    // 4 or 2

  __shared__ u16 ldsA[2][BM * BK];
  __shared__ u16 ldsB[2][BN * BK];

  const int tid = threadIdx.x;
  const int lane = tid & 63;
  const int wv = tid >> 6;
  const int wm = wv >> 2, wn = wv & 3;
  const int fr = lane & 15, hi = lane >> 4;

  // bijective XCD swizzle (m204)
  int wg;
  {
    const int q = nWG >> 3, r = nWG & 7;
    const int x = blockIdx.x & 7, ix = blockIdx.x >> 3;
    wg = (x < r ? x * (q + 1) : r * (q + 1) + (x - r) * q) + ix;
  }
  // split-K slice decode
  void* Cout = Cout0;
  if constexpr (SPLITK) {
    const int half = nWG >> 1;
    const int ks = (wg >= half) ? 1 : 0;
    wg -= ks * half;
    A += (long)ks * K;
    Bm += (long)ks * K;
    if (ks) Cout = Cout1;
  }
  const int bm = wg / nBN, bn = wg % nBN;
  const long aR0 = (long)bm * BM;
  const long bR0 = (long)bn * BN;

  // staging addresses: round r covers 64 rows; slot (row,s) holds global chunk s^(row&7)
  const int srow = tid >> 3;
  const int sch = (tid & 7) ^ (srow & 7);
  const long aoff = (aR0 + srow) * (long)lda + sch * 8;
  const long boff = (bR0 + srow) * (long)ldb + sch * 8;

  auto SA = [&](int buf, int r, int kOff) {
    gload16(A + aoff + ((long)r * 64) * lda + kOff, &ldsA[buf][r * 4096 + tid * 8]);
  };
  auto SB = [&](int buf, int r, int kOff) {
    gload16(Bm + boff + ((long)r * 64) * ldb + kOff, &ldsB[buf][r * 4096 + tid * 8]);
  };
  // swizzled ds_read_b128: chunk = (kk*4 + hi) ^ (row&7)
  auto rdfrag = [&](const u16* base, int row, int kk) -> bf16x8 {
    return *(const bf16x8*)&base[row * 64 + (((kk << 2) | hi) ^ (row & 7)) * 8];
  };

  f32x4 acc[8][NF];
#pragma unroll
  for (int m = 0; m < 8; ++m)
#pragma unroll
    for (int n = 0; n < NF; ++n)
      acc[m][n] = f32x4{0.f, 0.f, 0.f, 0.f};

  bf16x8 bfr[NF][2];
  const int nK = K / BK;

  // ---- prologue: stage tile 0, order B... A0 A2 A1 A3, wait all but last 2 ----
  if constexpr (BN == 256) {
    SB(0, 0, 0); SB(0, 1, 0); SB(0, 2, 0); SB(0, 3, 0);
  } else {
    SB(0, 0, 0); SB(0, 1, 0);
  }
  SA(0, 0, 0); SA(0, 2, 0); SA(0, 1, 0); SA(0, 3, 0);
  VM2;
  BARRIER;

  // ---- main loop: tile kt reads buf cur, stages tile kt+1 into cur^1 ----
  int cur = 0;
  for (int kt = 0; kt < nK - 1; ++kt) {
    const int kN = (kt + 1) * BK;
    const int nxt = cur ^ 1;
    const u16* la = ldsA[cur];
    const u16* lb = ldsB[cur];
    READ_B;
    if constexpr (BN == 256) {
      PHASE(0, { SB(nxt, 0, kN); SB(nxt, 1, kN); }, {});
      PHASE(1, { SB(nxt, 2, kN); SB(nxt, 3, kN); }, VM4);
      PHASE(2, { SA(nxt, 0, kN); SA(nxt, 2, kN); }, {});
      PHASE(3, { SA(nxt, 1, kN); SA(nxt, 3, kN); }, VM2);
    } else {
      PHASE(0, { SB(nxt, 0, kN); SB(nxt, 1, kN); }, {});
      PHASE(1, { SA(nxt, 0, kN); SA(nxt, 2, kN); }, VM4);
      PHASE(2, { SA(nxt, 1, kN); SA(nxt, 3, kN); }, {});
      PHASE(3, {}, VM2);
    }
    cur ^= 1;
  }

  // ---- final tile: no staging; A1,A3 still in flight until phase-1 wait ----
  {
    const u16* la = ldsA[cur];
    const u16* lb = ldsB[cur];
    READ_B;
    PHASE(0, {}, {});
    PHASE(1, {}, VM0);
    PHASE(2, {}, {});
    PHASE(3, {}, {});
  }

  // ---- epilogue; C/D: col=fr, row=hi*4+i ----
  const long row0 = aR0 + wm * 128;
  const long col0 = bR0 + wn * WNT;
  if constexpr (MODE == 0) {
    u16* Cg = (u16*)Cout;
#pragma unroll
    for (int m = 0; m < 8; ++m) {
#pragma unroll
      for (int i = 0; i < 4; ++i) {
        const long r = row0 + m * 16 + hi * 4 + i;
#pragma unroll
        for (int n = 0; n < NF; ++n)
          Cg[r * N + col0 + n * 16 + fr] = f2bf(gelu_fast(acc[m][n][i]));
      }
    }
  } else {
    float* Cf = (float*)Cout;
#pragma unroll
    for (int m = 0; m < 8; ++m) {
#pragma unroll
      for (int i = 0; i < 4; ++i) {
        const long r = row0 + m * 16 + hi * 4 + i;
        const float s = scale[r];
#pragma unroll
        for (int n = 0; n < NF; ++n)
          Cf[r * N + col0 + n * 16 + fr] = acc[m][n][i] * s;
      }
    }
  }
}

extern "C" void kernel_launch(void* const* d_in, const int* in_sizes, int n_in,
                              void* d_out, int out_size, void* d_ws, size_t ws_size,
                              hipStream_t stream) {
  const float* Qf = (const float*)d_in[0];
  const float* Kf = (const float*)d_in[1];
  const float* Vf = (const float*)d_in[2];
  float* Out = (float*)d_out;

  const int M = M_ROWS, D = D_DIM, S = S_DIM, DV = DV_DIM;

  // workspace layout
  char* p = (char*)d_ws;
  u16* Qb = (u16*)p;            p += (size_t)M * D * 2;    // 16 MB
  u16* Kb = (u16*)p;            p += (size_t)S * D * 2;    //  8 MB
  u16* VT = (u16*)p;            p += (size_t)DV * S * 2;   //  8 MB
  float* scalebuf = (float*)p;  p += (size_t)M * 4;        // 32 KB
  u16* G = (u16*)p;                                        // 64 MB when unchunked
  const size_t fixed = (size_t)(p - (char*)d_ws);
  const size_t avail = (ws_size > fixed) ? (ws_size - fixed) : 0;

  // M-chunking (multiples of 256) so the G panel fits
  const size_t bytes_per_row = (size_t)S * 2;
  size_t rows_fit = avail / bytes_per_row;
  int chunk = (int)((rows_fit / 256) * 256);
  if (chunk > M) chunk = M;
  if (chunk < 256) chunk = 256;

  // split-K path needs G (full) + 32 MB f32 partial after it
  const size_t Gbytes = (size_t)M * S * 2;
  const size_t Pbytes = (size_t)M * DV * 4;
  const bool use_split = (chunk >= M) && (avail >= Gbytes + Pbytes);
  float* P1 = (float*)((char*)G + Gbytes);

  cast_f32_bf16<<<(M * D / 4 + 255) / 256, 256, 0, stream>>>(Qf, Qb, M * D / 4);
  cast_f32_bf16<<<(S * D / 4 + 255) / 256, 256, 0, stream>>>(Kf, Kb, S * D / 4);
  transpose_cast<<<dim3(DV / 32, S / 32), 256, 0, stream>>>(Vf, VT, S, DV);

  const int nBN1 = S / 256;    // 16
  const int nBN2 = DV / 128;   // 8
  for (int m0 = 0; m0 < M; m0 += chunk) {
    const int rows = (M - m0 < chunk) ? (M - m0) : chunk;
    const int nWG1 = (rows / 256) * nBN1;
    gemm8p<0, 256, false><<<dim3(nWG1), 512, 0, stream>>>(
        Qb + (size_t)m0 * D, Kb, (void*)G, nullptr, nullptr, D, D, D, S, nBN1, nWG1);
    row_scale<<<rows, 256, 0, stream>>>(G, scalebuf, S);
    if (use_split) {
      // two K=2048 slices, BN=256 (16 MFMA/phase), one 256-block launch
      const int nBNs = DV / 256;               // 4
      const int nWGs = 2 * (M / 256) * nBNs;   // 256
      gemm8p<1, 256, true><<<dim3(nWGs), 512, 0, stream>>>(
          G, VT, (void*)Out, (void*)P1, scalebuf, S / 2, S, S, DV, nBNs, nWGs);
      add_inplace<<<2048, 256, 0, stream>>>(Out, P1, M * DV / 4);
    } else {
      const int nWG2 = (rows / 256) * nBN2;
      gemm8p<1, 128, false><<<dim3(nWG2), 512, 0, stream>>>(
          G, VT, (void*)(Out + (size_t)m0 * DV), nullptr, scalebuf, S, S, S, DV, nBN2, nWG2);
    }
  }
}